// Round 8
// baseline (349.379 us; speedup 1.0000x reference)
//
#include <hip/hip_runtime.h>
#include <math.h>

// Problem constants
#define D_MODEL 2048
#define N_HEADS 16
#define N_KV    4
#define DH      128
#define QKV_DIM 3072   // 2048 + 2*4*128
#define TT      2048   // T
#define BB      2      // B
#define ROWS    (BB*TT)  // 4096

// Packed QKV layout in d_out (u16 offsets). Written by gemm1 epilogue:
//   Qp[b][h][t][d]   : ((b*16+h)*2048 + t)*128 + d          @ 0
//   Kp[g][t][d]      : (g*2048 + t)*128 + d                 @ 8,388,608   (g=b*4+hk)
//   Vt[g][d][t]      : (g*128 + d)*2048 + t                 @ 10,485,760  (V pre-transposed)
// Total 12,582,912 u16 = 25,165,824 B (same region/lifetime as old QKV).
#define QP_OFF 0u
#define KP_OFF 8388608u
#define VT_OFF 10485760u

typedef unsigned short u16;
typedef short short8 __attribute__((ext_vector_type(8)));
typedef short short4v __attribute__((ext_vector_type(4)));
typedef float float4v __attribute__((ext_vector_type(4)));

__device__ inline u16 f2b(float f) {
    union { float f; unsigned u; } v; v.f = f;
    unsigned r = v.u + 0x7FFF + ((v.u >> 16) & 1);
    return (u16)(r >> 16);
}

// async global->LDS DMA, 16 bytes/lane. LDS dest = wave-uniform base + lane*16.
__device__ inline void async16(const void* g, void* l) {
    __builtin_amdgcn_global_load_lds(
        (const __attribute__((address_space(1))) void*)g,
        (__attribute__((address_space(3))) void*)l, 16, 0, 0);
}

// ---------------------------------------------------------------------------
// 32x32 transpose tile body (shared by prep/attn_wo fused kernels).
// dst[c][r] = bf16(src[r][c + col0]). 256 threads. tile = u16[32][33].
__device__ inline void transpose_tile(const float* __restrict__ src,
                                      u16* __restrict__ dst,
                                      int R, int C, int col0,
                                      int bx, int by, u16* tile) {
    int bc = bx * 32, br = by * 32;
    int tx = threadIdx.x & 31, ty = threadIdx.x >> 5;   // ty 0..7
    for (int i = ty; i < 32; i += 8)
        tile[i * 33 + tx] = f2b(src[(size_t)(br + i) * C + col0 + bc + tx]);
    __syncthreads();
    for (int i = ty; i < 32; i += 8)
        dst[(size_t)(bc + i) * R + br + tx] = tile[tx * 33 + i];
}

// ---------------------------------------------------------------------------
// Fused preprocessing (saves 2 launch gaps):
//   blocks [0, 8192)        : x fp32 -> xb bf16 (vectorized convert)
//   blocks [8192, 12288)    : Wqkv^T cols 0..2047  -> WqkvTA
//   blocks [12288, 14336)   : Wqkv^T cols 2048..3071 -> WqkvTB
__global__ __launch_bounds__(256) void prep_kernel(
    const float* __restrict__ x, u16* __restrict__ xb,
    const float* __restrict__ Wqkv, u16* __restrict__ WA, u16* __restrict__ WB) {
    __shared__ __align__(16) u16 tile[32 * 33];
    int bid = blockIdx.x;
    if (bid < 8192) {
        size_t i = (size_t)bid * 256 + threadIdx.x;
        float4v a = *(const float4v*)(x + i * 4);
        short4v p;
        p[0] = (short)f2b(a[0]); p[1] = (short)f2b(a[1]);
        p[2] = (short)f2b(a[2]); p[3] = (short)f2b(a[3]);
        *(short4v*)(xb + i * 4) = p;
    } else if (bid < 12288) {
        int t = bid - 8192;                     // dim3(64,64)
        transpose_tile(Wqkv, WA, D_MODEL, QKV_DIM, 0, t & 63, t >> 6, tile);
    } else {
        int t = bid - 12288;                    // dim3(32,64)
        transpose_tile(Wqkv, WB, D_MODEL, QKV_DIM, 2048, t & 31, t >> 5, tile);
    }
}

// ---------------------------------------------------------------------------
// gemm1 v2.1: 256^2 4-phase counted-vmcnt template, C = A[4096,2048] @ Bt^T,
// fused RoPE + packed Qp/Kp/Vt epilogue.
// FIX vs v2 (round 7 NaN): stage() LDS dest double-counted the slab offset
// (r0*128 already contains (wave*2+i)*1024; the extra term pushed waves 1-7
// out of their half-tile, leaving rows unwritten and corrupting neighbor
// LDS buffers -> garbage bf16 -> NaN). Dest is now r0*128 alone.
// Geometry: BM=BN=256, BK=64, 512 thr = 8 waves (2 M-groups x 4 N-groups),
// per-wave output 128x64 (acc[8][4] f32x4). LDS = A/B double-buffered
// [256][64] bf16 = 128 KB (1 block/CU, 2 waves/SIMD).
// Swizzle (T2): 16B chunk index XORed with row&7 -> ds_read_b128 2-way max
// (free). DMA dest linear; swizzle applied by pre-swizzling the GLOBAL
// source chunk per lane (rule #21).
// Pipeline (T3+T4): tile t's 4 phases issue stages A0(t+1) A1(t+1) [other
// buffer, dead] and B0(t+2) B1(t+2) [same buffer: B is register-resident
// after phase 0's trailing barrier -> region dead]. One counted
// s_waitcnt vmcnt(4) per tile (phase 3): the 4 youngest units are B(t+2),
// so A1(t+1) and everything older (incl. B(t+1)) is complete. Never 0 in
// steady state; vmcnt(0) only at t=NT-2 (tail, B stages skipped).
__global__ __launch_bounds__(512, 2) void gemm1_8ph(
    const u16* __restrict__ A, const u16* __restrict__ Bt1,
    const u16* __restrict__ Bt2, u16* __restrict__ Cv,
    const int* __restrict__ sp) {
    const int K = 2048, NT = 32;               // K / 64
    __shared__ __align__(16) u16 As[2][256 * 64];   // 64 KB
    __shared__ __align__(16) u16 Bs[2][256 * 64];   // 64 KB
    const int tid = threadIdx.x;
    const int wave = tid >> 6, lane = tid & 63;
    const int quad = lane >> 4, l16 = lane & 15;
    const int gm = wave >> 2, gn = wave & 3;
    const int bm = blockIdx.y * 256, bn = blockIdx.x * 256;
    const u16* Ag = A + (size_t)bm * K;
    const u16* Bt = (bn < 2048) ? (Bt1 + (size_t)bn * K)
                                : (Bt2 + (size_t)(bn - 2048) * K);

    // staging lane geometry: each instr = 8 rows x 8 chunks of 16B, linear
    // LDS dest; source chunk pre-swizzled so LDS[row][c] = G[row][c^(row&7)].
    const int srl = lane >> 3;                  // row within 8-row slab
    const int sch = (lane & 7) ^ srl;           // pre-swizzled source chunk

    // stage one 128x64 half (16 KB): 2 instrs/wave (8 waves cover 128 rows).
    // LDS byte base for slab = r0*128 (r0 = half*128 + slab*8); lane*16 is
    // added by hardware (rows srl, chunk lane&7 within the slab).
    auto stage = [&](const u16* src, int half, u16* ldsTile) {
#pragma unroll
        for (int i = 0; i < 2; i++) {
            int r0 = half * 128 + (wave * 2 + i) * 8;
            async16(src + (size_t)(r0 + srl) * K + sch * 8,
                    (char*)ldsTile + (size_t)r0 * 128);
        }
    };
    // read one 16x32 b128 fragment through the XOR swizzle
    auto ldfrag = [&](const u16* tile, int row16, int kk) -> short8 {
        return *(const short8*)(tile + (size_t)(row16 + l16) * 64
                                + (((kk * 4 + quad) ^ (l16 & 7)) * 8));
    };

    float4v acc[8][4] = {};
    short8 bf[4][2];

    // prologue: A0(0) A1(0) B0(0) B1(0) B0(1) B1(1); wait through B1(0)
    stage(Ag, 0, As[0]); stage(Ag, 1, As[0]);
    stage(Bt, 0, Bs[0]); stage(Bt, 1, Bs[0]);
    stage(Bt + 64, 0, Bs[1]); stage(Bt + 64, 1, Bs[1]);
    asm volatile("s_waitcnt vmcnt(4)" ::: "memory");
    __builtin_amdgcn_s_barrier();

    for (int t = 0; t < NT; t++) {
        const int cur = t & 1;
        const u16* Atile = As[cur] + gm * 128 * 64;   // this wave's A-half
        const u16* Btile = Bs[cur] + gn * 64 * 64;    // this wave's 64 B-rows
#pragma unroll
        for (int q = 0; q < 4; q++) {
            short8 af[2][2];
            if (q == 0) {
#pragma unroll
                for (int cf = 0; cf < 4; cf++)
#pragma unroll
                    for (int kk = 0; kk < 2; kk++)
                        bf[cf][kk] = ldfrag(Btile, cf * 16, kk);
            }
#pragma unroll
            for (int i = 0; i < 2; i++)
#pragma unroll
                for (int kk = 0; kk < 2; kk++)
                    af[i][kk] = ldfrag(Atile, (q * 2 + i) * 16, kk);
            // stage schedule: q0/q1 -> A halves of t+1 (other buffer);
            // q2/q3 -> B halves of t+2 (this buffer; B already in regs)
            if (q == 0)      { if (t + 1 < NT) stage(Ag + (size_t)(t + 1) * 64, 0, As[cur ^ 1]); }
            else if (q == 1) { if (t + 1 < NT) stage(Ag + (size_t)(t + 1) * 64, 1, As[cur ^ 1]); }
            else if (q == 2) { if (t + 2 < NT) stage(Bt + (size_t)(t + 2) * 64, 0, Bs[cur]); }
            else             { if (t + 2 < NT) stage(Bt + (size_t)(t + 2) * 64, 1, Bs[cur]); }
            __builtin_amdgcn_sched_barrier(0);
            __builtin_amdgcn_s_barrier();
            asm volatile("s_waitcnt lgkmcnt(0)" ::: "memory");
            __builtin_amdgcn_sched_barrier(0);          // rule #18
            __builtin_amdgcn_s_setprio(1);
#pragma unroll
            for (int i = 0; i < 2; i++)
#pragma unroll
                for (int cf = 0; cf < 4; cf++)
#pragma unroll
                    for (int kk = 0; kk < 2; kk++)
                        acc[q * 2 + i][cf] = __builtin_amdgcn_mfma_f32_16x16x32_bf16(
                            af[i][kk], bf[cf][kk], acc[q * 2 + i][cf], 0, 0, 0);
            __builtin_amdgcn_s_setprio(0);
            if (q == 3) {
                if (t < NT - 2)       asm volatile("s_waitcnt vmcnt(4)" ::: "memory");
                else if (t == NT - 2) asm volatile("s_waitcnt vmcnt(0)" ::: "memory");
            }
            __builtin_amdgcn_s_barrier();
        }
    }

    // epilogue: RoPE + packed QKV scatter (same per-element math as v1;
    // C/D layout col = ...cf*16+l16, row = ...rf*16+quad*4+r).
    const int sp0 = *sp;
#pragma unroll
    for (int cf = 0; cf < 4; cf++) {
        int col = bn + gn * 64 + cf * 16 + l16;
        bool do_rope = (col < 2560);
        float inv = 0.f;
        if (do_rope) inv = __expf(-0.14391156816f * (float)((col & 127) >> 1));
#pragma unroll
        for (int rf = 0; rf < 8; rf++) {
            int row0 = bm + gm * 128 + rf * 16 + quad * 4;
#pragma unroll
            for (int r = 0; r < 4; r++) {
                float v = acc[rf][cf][r];
                if (do_rope) {
                    float partner = __shfl_xor(v, 1, 64);
                    float ang = (float)(sp0 + ((row0 + r) & (TT - 1))) * inv;
                    float c = __cosf(ang), s = __sinf(ang);
                    v = (col & 1) ? (partner * s + v * c)
                                  : (v * c - partner * s);
                }
                int rw = row0 + r;
                int bb = rw >> 11, tt = rw & 2047;
                size_t addr;
                if (col < 2048)
                    addr = QP_OFF + (size_t)(bb * 16 + (col >> 7)) * 262144
                         + (size_t)tt * 128 + (col & 127);
                else if (col < 2560)
                    addr = KP_OFF + (size_t)(bb * 4 + ((col - 2048) >> 7)) * 262144
                         + (size_t)tt * 128 + (col & 127);
                else
                    addr = VT_OFF + (size_t)(bb * 4 + ((col - 2560) >> 7)) * 262144
                         + (size_t)(col & 127) * 2048 + tt;
                Cv[addr] = f2b(v);
            }
        }
    }
}

// ---------------------------------------------------------------------------
// m97-style async GEMM (gemm2 only now): C[M,N] = A[M,K] @ Bt[N,K]^T.
template<bool F32OUT, bool ROPE>
__global__ __launch_bounds__(256) void gemm_bt_async(
    const u16* __restrict__ A, const u16* __restrict__ Bt1, const u16* __restrict__ Bt2,
    int nsplit, void* __restrict__ Cv, int M, int N, int K, const int* __restrict__ sp) {
    __shared__ __align__(16) u16 As[128 * 32];
    __shared__ __align__(16) u16 Bs[128 * 32];
    const int tid = threadIdx.x;
    const int wave = tid >> 6, lane = tid & 63;
    const int quad = lane >> 4, l16 = lane & 15;
    const int bm = blockIdx.y * 128, bn = blockIdx.x * 128;
    const int wm = (wave >> 1) * 64, wn = (wave & 1) * 64;
    const int srow = wave * 32 + (lane >> 2);
    const int scol = (lane & 3) * 8;
    const u16* Bt = (bn < nsplit) ? (Bt1 + (size_t)bn * K)
                                  : (Bt2 + (size_t)(bn - nsplit) * K);

    float4v acc[4][4] = {};

    for (int k0 = 0; k0 < K; k0 += 32) {
        async16(A + (size_t)(bm + srow) * K + k0 + scol, (char*)As + wave * 2048);
        async16(A + (size_t)(bm + srow + 16) * K + k0 + scol, (char*)As + wave * 2048 + 1024);
        async16(Bt + (size_t)srow * K + k0 + scol, (char*)Bs + wave * 2048);
        async16(Bt + (size_t)(srow + 16) * K + k0 + scol, (char*)Bs + wave * 2048 + 1024);
        __syncthreads();
        short8 af[4], bf[4];
#pragma unroll
        for (int i = 0; i < 4; i++)
            af[i] = *(const short8*)(As + (wm + i * 16 + l16) * 32 + quad * 8);
#pragma unroll
        for (int j = 0; j < 4; j++)
            bf[j] = *(const short8*)(Bs + (wn + j * 16 + l16) * 32 + quad * 8);
#pragma unroll
        for (int i = 0; i < 4; i++)
#pragma unroll
            for (int j = 0; j < 4; j++)
                acc[i][j] = __builtin_amdgcn_mfma_f32_16x16x32_bf16(af[i], bf[j], acc[i][j], 0, 0, 0);
        __syncthreads();
    }
    const int sp0 = ROPE ? *sp : 0;
    // epilogue: C/D layout col=lane&15, row=quad*4+reg (m89/m91-verified).
#pragma unroll
    for (int j = 0; j < 4; j++) {
        int col = bn + wn + j * 16 + l16;
        bool do_rope = ROPE && (col < 2560);
        float inv = 0.f;
        if (do_rope) inv = __expf(-0.14391156816f * (float)((col & 127) >> 1));
#pragma unroll
        for (int i = 0; i < 4; i++) {
            int row0 = bm + wm + i * 16 + quad * 4;
#pragma unroll
            for (int r = 0; r < 4; r++) {
                float v = acc[i][j][r];
                if (do_rope) {
                    float partner = __shfl_xor(v, 1, 64);
                    float ang = (float)(sp0 + ((row0 + r) & (TT - 1))) * inv;
                    float c = __cosf(ang), s = __sinf(ang);
                    v = (col & 1) ? (partner * s + v * c)
                                  : (v * c - partner * s);
                }
                if (F32OUT) {
                    ((float*)Cv)[(size_t)(row0 + r) * N + col] = v;
                } else {
                    int rw = row0 + r;
                    int bb = rw >> 11, t = rw & 2047;
                    size_t addr;
                    if (col < 2048)
                        addr = QP_OFF + (size_t)(bb * 16 + (col >> 7)) * 262144
                             + (size_t)t * 128 + (col & 127);
                    else if (col < 2560)
                        addr = KP_OFF + (size_t)(bb * 4 + ((col - 2048) >> 7)) * 262144
                             + (size_t)t * 128 + (col & 127);
                    else
                        addr = VT_OFF + (size_t)(bb * 4 + ((col - 2560) >> 7)) * 262144
                             + (size_t)(col & 127) * 2048 + t;
                    ((u16*)Cv)[addr] = f2b(v);
                }
            }
        }
    }
}

// ---------------------------------------------------------------------------
// Fused flash-attention + Wo^T transpose.
//   blocks [0, 512)     : flash attention v10 (unchanged)
//   blocks [512, 4608)  : Wo^T transpose -> WoT
__global__ __launch_bounds__(256, 2) void attn_wo_kernel(
    const u16* __restrict__ qkv, u16* __restrict__ y,
    const float* __restrict__ Wo, u16* __restrict__ WoT) {
    __shared__ __align__(16) u16 Ks[2][32 * 128];   // 2 x 8192 B
    __shared__ __align__(16) u16 Vs[2][128 * 32];   // 2 x 8192 B (V^T: d rows)
    __shared__ __align__(16) u16 Ps[4][32 * 32];    // 8192 B   (total 40960)

    if (blockIdx.x >= 512) {                        // Wo^T transpose blocks
        int t = blockIdx.x - 512;                   // dim3(64,64)
        transpose_tile(Wo, WoT, D_MODEL, D_MODEL, 0, t & 63, t >> 6, (u16*)Ks[0]);
        return;
    }

    const int tid = threadIdx.x;
    const int wave = tid >> 6, lane = tid & 63;
    const int quad = lane >> 4, l16 = lane & 15;
    const int bx = blockIdx.x;
    const int xg = bx & 7;             // XCD group = (b, hk)
    const int b = xg >> 2, hk = xg & 3;
    const int jj = bx >> 3;            // 0..63 within group = XCD stream pos
    // dual-pairing-robust balance map (jj^1 and jj^32 both flip parity only)
    const int h = hk * 4 + 2 * ((jj >> 2) & 1) + (jj & 1);
    const int u = ((jj >> 1) & 1) | (((jj >> 3) & 1) << 1) | (((jj >> 4) & 1) << 2);
    const int p = ((jj >> 5) ^ jj) & 1;
    const int qt = p ? (15 - u) : u;
    const int g = b * 4 + hk;
    const float scale = 0.08838834764831845f;  // 1/sqrt(128)

    // Q fragments in registers (reused every kv-tile): 2 row-groups of 16
    const int wq0 = qt * 128 + wave * 32;
    const u16* qbase = qkv + QP_OFF + (size_t)(b * 16 + h) * 262144;
    short8 qf[2][4];
#pragma unroll
    for (int gi = 0; gi < 2; gi++) {
        const u16* qrow = qbase + (size_t)(wq0 + gi * 16 + l16) * 128;
#pragma unroll
        for (int d = 0; d < 4; d++)
            qf[gi][d] = *(const short8*)(qrow + d * 32 + quad * 8);
    }

    // Oacc[gi][0..7]: O tiles (2 x 16 x 128). Ol[gi]: row-sum l via ones MFMA.
    float4v Oacc[2][8] = {};
    float4v Ol[2] = {};
    const short8 ONES = {(short)0x3F80, (short)0x3F80, (short)0x3F80, (short)0x3F80,
                         (short)0x3F80, (short)0x3F80, (short)0x3F80, (short)0x3F80};

    const int ktmax = 4 * qt + 3;      // kv tiles - 1 (32 kv rows per tile)

    size_t kg[2];
#pragma unroll
    for (int si = 0; si < 2; si++) {
        int kr = wave * 8 + si * 4 + quad;
        kg[si] = (size_t)kr * 128 + (size_t)((l16 ^ (kr & 7)) * 8);
    }
    size_t vg[2];
#pragma unroll
    for (int si = 0; si < 2; si++) {
        int vr = wave * 32 + si * 16 + (lane >> 2);
        vg[si] = (size_t)vr * 2048 + (size_t)((((lane & 3) ^ ((lane >> 3) & 3)) * 8));
    }
    const u16* Kb = qkv + KP_OFF + (size_t)g * 262144;
    const u16* Vb = qkv + VT_OFF + (size_t)g * 262144;

    // kt=0 prefetch (both K and V^T via DMA)
#pragma unroll
    for (int si = 0; si < 2; si++)
        async16(Kb + kg[si], (char*)Ks[0] + wave * 2048 + si * 1024);
#pragma unroll
    for (int si = 0; si < 2; si++)
        async16(Vb + vg[si], (char*)Vs[0] + wave * 2048 + si * 1024);

    for (int kt = 0; kt <= ktmax; kt++) {
        const int cur = kt & 1;
        __syncthreads();   // vmcnt(0)+barrier: DMA for buf[cur] complete
        if (kt < ktmax) {  // prefetch next tile into buf[cur^1]
#pragma unroll
            for (int si = 0; si < 2; si++)
                async16(Kb + (size_t)(kt + 1) * 4096 + kg[si],
                        (char*)Ks[cur ^ 1] + wave * 2048 + si * 1024);
#pragma unroll
            for (int si = 0; si < 2; si++)
                async16(Vb + (size_t)(kt + 1) * 32 + vg[si],
                        (char*)Vs[cur ^ 1] + wave * 2048 + si * 1024);
        }
        const u16* Kcur = Ks[cur];
        const u16* Vcur = Vs[cur];

        float4v S[2][2] = {};
#pragma unroll
        for (int d = 0; d < 4; d++) {
#pragma unroll
            for (int j = 0; j < 2; j++) {
                short8 bk = *(const short8*)(Kcur + (j * 16 + l16) * 128
                                             + (((d * 4 + quad) ^ (l16 & 7)) * 8));
#pragma unroll
                for (int gi = 0; gi < 2; gi++)
                    S[gi][j] = __builtin_amdgcn_mfma_f32_16x16x32_bf16(qf[gi][d], bk, S[gi][j], 0, 0, 0);
            }
        }
        const int kvb = kt * 32 + l16;
        const bool diag = (kt * 32 + 31 > wq0);
#pragma unroll
        for (int gi = 0; gi < 2; gi++) {
            const int qbq = wq0 + gi * 16 + quad * 4;
#pragma unroll
            for (int j = 0; j < 2; j++)
#pragma unroll
                for (int r = 0; r < 4; r++) {
                    bool masked = diag && (kvb + j * 16 > qbq + r);
                    float pv = masked ? 0.f : __expf(S[gi][j][r] * scale);
                    int rq = gi * 16 + quad * 4 + r;
                    int ch = (j * 2 + (l16 >> 3)) ^ ((rq >> 1) & 3);
                    Ps[wave][rq * 32 + ch * 8 + (l16 & 7)] = f2b(pv);
                }
        }
        __asm__ volatile("s_waitcnt lgkmcnt(0)" ::: "memory");
        short8 ap[2];
#pragma unroll
        for (int gi = 0; gi < 2; gi++) {
            int rq = gi * 16 + l16;
            ap[gi] = *(const short8*)(Ps[wave] + rq * 32
                                      + ((quad ^ ((l16 >> 1) & 3)) * 8));
        }
#pragma unroll
        for (int dt = 0; dt < 8; dt++) {
            short8 bv = *(const short8*)(Vcur + (dt * 16 + l16) * 32
                                         + ((quad ^ ((l16 >> 1) & 3)) * 8));
#pragma unroll
            for (int gi = 0; gi < 2; gi++)
                Oacc[gi][dt] = __builtin_amdgcn_mfma_f32_16x16x32_bf16(ap[gi], bv, Oacc[gi][dt], 0, 0, 0);
        }
#pragma unroll
        for (int gi = 0; gi < 2; gi++)
            Ol[gi] = __builtin_amdgcn_mfma_f32_16x16x32_bf16(ap[gi], ONES, Ol[gi], 0, 0, 0);
    }
#pragma unroll
    for (int gi = 0; gi < 2; gi++)
#pragma unroll
        for (int dt = 0; dt < 8; dt++)
#pragma unroll
            for (int r = 0; r < 4; r++) {
                float v = Oacc[gi][dt][r] / Ol[gi][r];
                y[(size_t)(b * TT + wq0 + gi * 16 + quad * 4 + r) * D_MODEL
                  + h * 128 + dt * 16 + l16] = f2b(v);
            }
}

// ---------------------------------------------------------------------------
// Memory plan (ws use = 25,165,824 B, proven available; inputs/out fp32):
//   ws[0, 16.78M):      xb (phases 1-2) -> Y (attn -> gemm2)
//   ws[16.78M, 25.17M): WqkvT rows 0..2047 (gemm1) -> WoT (gemm2)
//   d_out[0, 25.17M):   packed Qp/Kp/Vt bf16 (gemm1 -> attn) -> final fp32 out
//   d_out[25.17M, 33.55M): WqkvT rows 2048..3071 (gemm1 only; dead after)
// Launches: 4 — prep, gemm1 (256^2 counted-vmcnt), attn+WoT, gemm2.
extern "C" void kernel_launch(void* const* d_in, const int* in_sizes, int n_in,
                              void* d_out, int out_size, void* d_ws, size_t ws_size,
                              hipStream_t stream) {
    const float* x    = (const float*)d_in[0];   // 4096 x 2048 fp32
    const float* Wqkv = (const float*)d_in[1];   // 2048 x 3072 fp32
    const float* Wo   = (const float*)d_in[2];   // 2048 x 2048 fp32
    const int*   sp   = (const int*)d_in[3];

    char* ws = (char*)d_ws;
    char* dob = (char*)d_out;
    u16*   xb     = (u16*)ws;                    // 4096x2048 bf16
    u16*   Y      = (u16*)ws;                    //    (after gemm1: attn output)
    u16*   WqkvTA = (u16*)(ws + 16777216);       // N-rows 0..2047 of Wqkv^T
    u16*   WoT    = (u16*)(ws + 16777216);       //    (after gemm1)
    u16*   QKVp   = (u16*)d_out;                 // packed Qp/Kp/Vt bf16
    u16*   WqkvTB = (u16*)(dob + 25165824);      // N-rows 2048..3071 of Wqkv^T
    float* out    = (float*)d_out;

    // 1. fused prep: x->bf16 + Wqkv^T (both halves)
    prep_kernel<<<14336, 256, 0, stream>>>(x, xb, Wqkv, WqkvTA, WqkvTB);
    // 2. packed QKV = x @ Wqkv, fused RoPE — 256^2 counted-vmcnt pipeline
    gemm1_8ph<<<dim3(QKV_DIM / 256, ROWS / 256), 512, 0, stream>>>(
        xb, WqkvTA, WqkvTB, QKVp, sp);
    // 3. fused flash attention (-> Y, overwrites xb) + Wo^T (-> dead WqkvTA)
    attn_wo_kernel<<<4608, 256, 0, stream>>>(QKVp, Y, Wo, WoT);
    // 4. out = Y @ Wo -> fp32 (overwrites packed QKV + WqkvTB, dead)
    gemm_bt_async<true, false><<<dim3(D_MODEL / 128, ROWS / 128), 256, 0, stream>>>(
        Y, WoT, WoT, D_MODEL, out, ROWS, D_MODEL, D_MODEL, sp);
}

// Round 9
// 329.823 us; speedup vs baseline: 1.0593x; 1.0593x over previous
//
#include <hip/hip_runtime.h>
#include <math.h>

// Problem constants
#define D_MODEL 2048
#define N_HEADS 16
#define N_KV    4
#define DH      128
#define QKV_DIM 3072   // 2048 + 2*4*128
#define TT      2048   // T
#define BB      2      // B
#define ROWS    (BB*TT)  // 4096

// Packed QKV layout in d_out (u16 offsets). Written by gemm1 epilogue:
//   Qp[b][h][t][d]   : ((b*16+h)*2048 + t)*128 + d          @ 0
//   Kp[g][t][d]      : (g*2048 + t)*128 + d                 @ 8,388,608   (g=b*4+hk)
//   Vt[g][d][t]      : (g*128 + d)*2048 + t                 @ 10,485,760  (V pre-transposed)
// Total 12,582,912 u16 = 25,165,824 B (same region/lifetime as old QKV).
#define QP_OFF 0u
#define KP_OFF 8388608u
#define VT_OFF 10485760u

typedef unsigned short u16;
typedef short short8 __attribute__((ext_vector_type(8)));
typedef short short4v __attribute__((ext_vector_type(4)));
typedef float float4v __attribute__((ext_vector_type(4)));

__device__ inline u16 f2b(float f) {
    union { float f; unsigned u; } v; v.f = f;
    unsigned r = v.u + 0x7FFF + ((v.u >> 16) & 1);
    return (u16)(r >> 16);
}

// async global->LDS DMA, 16 bytes/lane. LDS dest = wave-uniform base + lane*16.
__device__ inline void async16(const void* g, void* l) {
    __builtin_amdgcn_global_load_lds(
        (const __attribute__((address_space(1))) void*)g,
        (__attribute__((address_space(3))) void*)l, 16, 0, 0);
}

// ---------------------------------------------------------------------------
// 32x32 transpose tile body (shared by prep/attn_wo fused kernels).
// dst[c][r] = bf16(src[r][c + col0]). 256 threads. tile = u16[32][33].
__device__ inline void transpose_tile(const float* __restrict__ src,
                                      u16* __restrict__ dst,
                                      int R, int C, int col0,
                                      int bx, int by, u16* tile) {
    int bc = bx * 32, br = by * 32;
    int tx = threadIdx.x & 31, ty = threadIdx.x >> 5;   // ty 0..7
    for (int i = ty; i < 32; i += 8)
        tile[i * 33 + tx] = f2b(src[(size_t)(br + i) * C + col0 + bc + tx]);
    __syncthreads();
    for (int i = ty; i < 32; i += 8)
        dst[(size_t)(bc + i) * R + br + tx] = tile[tx * 33 + i];
}

// ---------------------------------------------------------------------------
// Fused preprocessing (saves 2 launch gaps):
//   blocks [0, 8192)        : x fp32 -> xb bf16 (vectorized convert)
//   blocks [8192, 12288)    : Wqkv^T cols 0..2047  -> WqkvTA
//   blocks [12288, 14336)   : Wqkv^T cols 2048..3071 -> WqkvTB
__global__ __launch_bounds__(256) void prep_kernel(
    const float* __restrict__ x, u16* __restrict__ xb,
    const float* __restrict__ Wqkv, u16* __restrict__ WA, u16* __restrict__ WB) {
    __shared__ __align__(16) u16 tile[32 * 33];
    int bid = blockIdx.x;
    if (bid < 8192) {
        size_t i = (size_t)bid * 256 + threadIdx.x;
        float4v a = *(const float4v*)(x + i * 4);
        short4v p;
        p[0] = (short)f2b(a[0]); p[1] = (short)f2b(a[1]);
        p[2] = (short)f2b(a[2]); p[3] = (short)f2b(a[3]);
        *(short4v*)(xb + i * 4) = p;
    } else if (bid < 12288) {
        int t = bid - 8192;                     // dim3(64,64)
        transpose_tile(Wqkv, WA, D_MODEL, QKV_DIM, 0, t & 63, t >> 6, tile);
    } else {
        int t = bid - 12288;                    // dim3(32,64)
        transpose_tile(Wqkv, WB, D_MODEL, QKV_DIM, 2048, t & 31, t >> 5, tile);
    }
}

// ---------------------------------------------------------------------------
// m97-style async GEMM v2: C[M,N] = A[M,K] @ Bt[N,K]^T, bf16 in, fp32 accum.
// vs v1 (round 6, 94us, MfmaUtil 22.5, 6.29M bank conflicts):
//  - BK 32 -> 64: halves barrier-drain count per K (128 -> 64 barriers).
//    LDS 16KB -> 32KB, still 2-3 blocks/CU co-resident (the TLP that makes
//    this structure fast — m114; round 8 proved killing it costs 3x).
//  - chunk-XOR swizzle (proven correct + 0-conflict in round 8's gemm1_8ph):
//    LDS[row][c] = G[row][c ^ (row&7)] via pre-swizzled DMA source (rule
//    #21), read back with the same XOR -> fragment reads spread all 32
//    banks (was ~8-way conflicted at 64B row stride).
// B^T split across two buffers at N-row `nsplit` (workspace tetris).
// ROPE: fused rotary on cols < 2560 (fast hw trig).
// !F32OUT (gemm1): writes the PACKED QKV layout (Qp/Kp/Vt).
template<bool F32OUT, bool ROPE>
__global__ __launch_bounds__(256) void gemm_bt_async(
    const u16* __restrict__ A, const u16* __restrict__ Bt1, const u16* __restrict__ Bt2,
    int nsplit, void* __restrict__ Cv, int M, int N, int K, const int* __restrict__ sp) {
    __shared__ __align__(16) u16 As[128 * 64];   // 16 KB
    __shared__ __align__(16) u16 Bs[128 * 64];   // 16 KB
    const int tid = threadIdx.x;
    const int wave = tid >> 6, lane = tid & 63;
    const int quad = lane >> 4, l16 = lane & 15;
    const int bm = blockIdx.y * 128, bn = blockIdx.x * 128;
    const int wm = (wave >> 1) * 64, wn = (wave & 1) * 64;
    const int srl = lane >> 3;                  // row within 8-row slab
    const int sch = (lane & 7) ^ srl;           // pre-swizzled source chunk
    const u16* Bt = (bn < nsplit) ? (Bt1 + (size_t)bn * K)
                                  : (Bt2 + (size_t)(bn - nsplit) * K);

    float4v acc[4][4] = {};

    for (int k0 = 0; k0 < K; k0 += 64) {
        // stage A and B tiles: 4 instrs each per wave, 8 rows x 8 chunks per
        // instr, linear LDS dest (slab base r0*128 B), source chunk ^row&7.
#pragma unroll
        for (int i = 0; i < 4; i++) {
            int r0 = wave * 32 + i * 8;
            async16(A + (size_t)(bm + r0 + srl) * K + k0 + sch * 8,
                    (char*)As + (size_t)r0 * 128);
            async16(Bt + (size_t)(r0 + srl) * K + k0 + sch * 8,
                    (char*)Bs + (size_t)r0 * 128);
        }
        __syncthreads();
#pragma unroll
        for (int kk = 0; kk < 2; kk++) {
            short8 af[4], bf[4];
#pragma unroll
            for (int i = 0; i < 4; i++)
                af[i] = *(const short8*)(As + (size_t)(wm + i * 16 + l16) * 64
                                         + (((kk * 4 + quad) ^ (l16 & 7)) * 8));
#pragma unroll
            for (int j = 0; j < 4; j++)
                bf[j] = *(const short8*)(Bs + (size_t)(wn + j * 16 + l16) * 64
                                         + (((kk * 4 + quad) ^ (l16 & 7)) * 8));
#pragma unroll
            for (int i = 0; i < 4; i++)
#pragma unroll
                for (int j = 0; j < 4; j++)
                    acc[i][j] = __builtin_amdgcn_mfma_f32_16x16x32_bf16(
                        af[i], bf[j], acc[i][j], 0, 0, 0);
        }
        __syncthreads();
    }
    const int sp0 = ROPE ? *sp : 0;
    // epilogue: C/D layout col=lane&15, row=quad*4+reg (m89/m91-verified).
#pragma unroll
    for (int j = 0; j < 4; j++) {
        int col = bn + wn + j * 16 + l16;
        bool do_rope = ROPE && (col < 2560);
        float inv = 0.f;
        if (do_rope) inv = __expf(-0.14391156816f * (float)((col & 127) >> 1));
#pragma unroll
        for (int i = 0; i < 4; i++) {
            int row0 = bm + wm + i * 16 + quad * 4;
#pragma unroll
            for (int r = 0; r < 4; r++) {
                float v = acc[i][j][r];
                if (do_rope) {
                    float partner = __shfl_xor(v, 1, 64);
                    float ang = (float)(sp0 + ((row0 + r) & (TT - 1))) * inv;
                    float c = __cosf(ang), s = __sinf(ang);
                    v = (col & 1) ? (partner * s + v * c)
                                  : (v * c - partner * s);
                }
                if (F32OUT) {
                    ((float*)Cv)[(size_t)(row0 + r) * N + col] = v;
                } else {
                    // packed QKV store (region is wave-uniform per j-block)
                    int rw = row0 + r;
                    int bb = rw >> 11, t = rw & 2047;
                    size_t addr;
                    if (col < 2048)
                        addr = QP_OFF + (size_t)(bb * 16 + (col >> 7)) * 262144
                             + (size_t)t * 128 + (col & 127);
                    else if (col < 2560)
                        addr = KP_OFF + (size_t)(bb * 4 + ((col - 2048) >> 7)) * 262144
                             + (size_t)t * 128 + (col & 127);
                    else
                        addr = VT_OFF + (size_t)(bb * 4 + ((col - 2560) >> 7)) * 262144
                             + (size_t)(col & 127) * 2048 + t;
                    ((u16*)Cv)[addr] = f2b(v);
                }
            }
        }
    }
}

// ---------------------------------------------------------------------------
// Fused flash-attention + Wo^T transpose.
//   blocks [0, 512)     : flash attention v10 (unchanged)
//   blocks [512, 4608)  : Wo^T transpose -> WoT
__global__ __launch_bounds__(256, 2) void attn_wo_kernel(
    const u16* __restrict__ qkv, u16* __restrict__ y,
    const float* __restrict__ Wo, u16* __restrict__ WoT) {
    __shared__ __align__(16) u16 Ks[2][32 * 128];   // 2 x 8192 B
    __shared__ __align__(16) u16 Vs[2][128 * 32];   // 2 x 8192 B (V^T: d rows)
    __shared__ __align__(16) u16 Ps[4][32 * 32];    // 8192 B   (total 40960)

    if (blockIdx.x >= 512) {                        // Wo^T transpose blocks
        int t = blockIdx.x - 512;                   // dim3(64,64)
        transpose_tile(Wo, WoT, D_MODEL, D_MODEL, 0, t & 63, t >> 6, (u16*)Ks[0]);
        return;
    }

    const int tid = threadIdx.x;
    const int wave = tid >> 6, lane = tid & 63;
    const int quad = lane >> 4, l16 = lane & 15;
    const int bx = blockIdx.x;
    const int xg = bx & 7;             // XCD group = (b, hk)
    const int b = xg >> 2, hk = xg & 3;
    const int jj = bx >> 3;            // 0..63 within group = XCD stream pos
    // dual-pairing-robust balance map (jj^1 and jj^32 both flip parity only)
    const int h = hk * 4 + 2 * ((jj >> 2) & 1) + (jj & 1);
    const int u = ((jj >> 1) & 1) | (((jj >> 3) & 1) << 1) | (((jj >> 4) & 1) << 2);
    const int p = ((jj >> 5) ^ jj) & 1;
    const int qt = p ? (15 - u) : u;
    const int g = b * 4 + hk;
    const float scale = 0.08838834764831845f;  // 1/sqrt(128)

    // Q fragments in registers (reused every kv-tile): 2 row-groups of 16
    const int wq0 = qt * 128 + wave * 32;
    const u16* qbase = qkv + QP_OFF + (size_t)(b * 16 + h) * 262144;
    short8 qf[2][4];
#pragma unroll
    for (int gi = 0; gi < 2; gi++) {
        const u16* qrow = qbase + (size_t)(wq0 + gi * 16 + l16) * 128;
#pragma unroll
        for (int d = 0; d < 4; d++)
            qf[gi][d] = *(const short8*)(qrow + d * 32 + quad * 8);
    }

    // Oacc[gi][0..7]: O tiles (2 x 16 x 128). Ol[gi]: row-sum l via ones MFMA.
    float4v Oacc[2][8] = {};
    float4v Ol[2] = {};
    const short8 ONES = {(short)0x3F80, (short)0x3F80, (short)0x3F80, (short)0x3F80,
                         (short)0x3F80, (short)0x3F80, (short)0x3F80, (short)0x3F80};

    const int ktmax = 4 * qt + 3;      // kv tiles - 1 (32 kv rows per tile)

    size_t kg[2];
#pragma unroll
    for (int si = 0; si < 2; si++) {
        int kr = wave * 8 + si * 4 + quad;
        kg[si] = (size_t)kr * 128 + (size_t)((l16 ^ (kr & 7)) * 8);
    }
    size_t vg[2];
#pragma unroll
    for (int si = 0; si < 2; si++) {
        int vr = wave * 32 + si * 16 + (lane >> 2);
        vg[si] = (size_t)vr * 2048 + (size_t)((((lane & 3) ^ ((lane >> 3) & 3)) * 8));
    }
    const u16* Kb = qkv + KP_OFF + (size_t)g * 262144;
    const u16* Vb = qkv + VT_OFF + (size_t)g * 262144;

    // kt=0 prefetch (both K and V^T via DMA)
#pragma unroll
    for (int si = 0; si < 2; si++)
        async16(Kb + kg[si], (char*)Ks[0] + wave * 2048 + si * 1024);
#pragma unroll
    for (int si = 0; si < 2; si++)
        async16(Vb + vg[si], (char*)Vs[0] + wave * 2048 + si * 1024);

    for (int kt = 0; kt <= ktmax; kt++) {
        const int cur = kt & 1;
        __syncthreads();   // vmcnt(0)+barrier: DMA for buf[cur] complete
        if (kt < ktmax) {  // prefetch next tile into buf[cur^1]
#pragma unroll
            for (int si = 0; si < 2; si++)
                async16(Kb + (size_t)(kt + 1) * 4096 + kg[si],
                        (char*)Ks[cur ^ 1] + wave * 2048 + si * 1024);
#pragma unroll
            for (int si = 0; si < 2; si++)
                async16(Vb + (size_t)(kt + 1) * 32 + vg[si],
                        (char*)Vs[cur ^ 1] + wave * 2048 + si * 1024);
        }
        const u16* Kcur = Ks[cur];
        const u16* Vcur = Vs[cur];

        float4v S[2][2] = {};
#pragma unroll
        for (int d = 0; d < 4; d++) {
#pragma unroll
            for (int j = 0; j < 2; j++) {
                short8 bk = *(const short8*)(Kcur + (j * 16 + l16) * 128
                                             + (((d * 4 + quad) ^ (l16 & 7)) * 8));
#pragma unroll
                for (int gi = 0; gi < 2; gi++)
                    S[gi][j] = __builtin_amdgcn_mfma_f32_16x16x32_bf16(qf[gi][d], bk, S[gi][j], 0, 0, 0);
            }
        }
        const int kvb = kt * 32 + l16;
        const bool diag = (kt * 32 + 31 > wq0);
#pragma unroll
        for (int gi = 0; gi < 2; gi++) {
            const int qbq = wq0 + gi * 16 + quad * 4;
#pragma unroll
            for (int j = 0; j < 2; j++)
#pragma unroll
                for (int r = 0; r < 4; r++) {
                    bool masked = diag && (kvb + j * 16 > qbq + r);
                    float pv = masked ? 0.f : __expf(S[gi][j][r] * scale);
                    int rq = gi * 16 + quad * 4 + r;
                    int ch = (j * 2 + (l16 >> 3)) ^ ((rq >> 1) & 3);
                    Ps[wave][rq * 32 + ch * 8 + (l16 & 7)] = f2b(pv);
                }
        }
        __asm__ volatile("s_waitcnt lgkmcnt(0)" ::: "memory");
        short8 ap[2];
#pragma unroll
        for (int gi = 0; gi < 2; gi++) {
            int rq = gi * 16 + l16;
            ap[gi] = *(const short8*)(Ps[wave] + rq * 32
                                      + ((quad ^ ((l16 >> 1) & 3)) * 8));
        }
#pragma unroll
        for (int dt = 0; dt < 8; dt++) {
            short8 bv = *(const short8*)(Vcur + (dt * 16 + l16) * 32
                                         + ((quad ^ ((l16 >> 1) & 3)) * 8));
#pragma unroll
            for (int gi = 0; gi < 2; gi++)
                Oacc[gi][dt] = __builtin_amdgcn_mfma_f32_16x16x32_bf16(ap[gi], bv, Oacc[gi][dt], 0, 0, 0);
        }
#pragma unroll
        for (int gi = 0; gi < 2; gi++)
            Ol[gi] = __builtin_amdgcn_mfma_f32_16x16x32_bf16(ap[gi], ONES, Ol[gi], 0, 0, 0);
    }
#pragma unroll
    for (int gi = 0; gi < 2; gi++)
#pragma unroll
        for (int dt = 0; dt < 8; dt++)
#pragma unroll
            for (int r = 0; r < 4; r++) {
                float v = Oacc[gi][dt][r] / Ol[gi][r];
                y[(size_t)(b * TT + wq0 + gi * 16 + quad * 4 + r) * D_MODEL
                  + h * 128 + dt * 16 + l16] = f2b(v);
            }
}

// ---------------------------------------------------------------------------
// Memory plan (ws use = 25,165,824 B, proven available; inputs/out fp32):
//   ws[0, 16.78M):      xb (phases 1-2) -> Y (attn -> gemm2)
//   ws[16.78M, 25.17M): WqkvT rows 0..2047 (gemm1) -> WoT (gemm2)
//   d_out[0, 25.17M):   packed Qp/Kp/Vt bf16 (gemm1 -> attn) -> final fp32 out
//   d_out[25.17M, 33.55M): WqkvT rows 2048..3071 (gemm1 only; dead after)
// Launches: 4 — prep, gemm1 (BK=64 swizzled m97), attn+WoT, gemm2 (same).
extern "C" void kernel_launch(void* const* d_in, const int* in_sizes, int n_in,
                              void* d_out, int out_size, void* d_ws, size_t ws_size,
                              hipStream_t stream) {
    const float* x    = (const float*)d_in[0];   // 4096 x 2048 fp32
    const float* Wqkv = (const float*)d_in[1];   // 2048 x 3072 fp32
    const float* Wo   = (const float*)d_in[2];   // 2048 x 2048 fp32
    const int*   sp   = (const int*)d_in[3];

    char* ws = (char*)d_ws;
    char* dob = (char*)d_out;
    u16*   xb     = (u16*)ws;                    // 4096x2048 bf16
    u16*   Y      = (u16*)ws;                    //    (after gemm1: attn output)
    u16*   WqkvTA = (u16*)(ws + 16777216);       // N-rows 0..2047 of Wqkv^T
    u16*   WoT    = (u16*)(ws + 16777216);       //    (after gemm1)
    u16*   QKVp   = (u16*)d_out;                 // packed Qp/Kp/Vt bf16
    u16*   WqkvTB = (u16*)(dob + 25165824);      // N-rows 2048..3071 of Wqkv^T
    float* out    = (float*)d_out;

    // 1. fused prep: x->bf16 + Wqkv^T (both halves)
    prep_kernel<<<14336, 256, 0, stream>>>(x, xb, Wqkv, WqkvTA, WqkvTB);
    // 2. packed QKV = x @ Wqkv with fused RoPE (BK=64 swizzled m97 structure)
    gemm_bt_async<false, true><<<dim3(QKV_DIM / 128, ROWS / 128), 256, 0, stream>>>(
        xb, WqkvTA, WqkvTB, 2048, QKVp, ROWS, QKV_DIM, D_MODEL, sp);
    // 3. fused flash attention (-> Y, overwrites xb) + Wo^T (-> dead WqkvTA)
    attn_wo_kernel<<<4608, 256, 0, stream>>>(QKVp, Y, Wo, WoT);
    // 4. out = Y @ Wo -> fp32 (overwrites packed QKV + WqkvTB, dead)
    gemm_bt_async<true, false><<<dim3(D_MODEL / 128, ROWS / 128), 256, 0, stream>>>(
        Y, WoT, WoT, D_MODEL, out, ROWS, D_MODEL, D_MODEL, sp);
}

// Round 10
// 328.467 us; speedup vs baseline: 1.0637x; 1.0041x over previous
//
#include <hip/hip_runtime.h>
#include <math.h>

// Problem constants
#define D_MODEL 2048
#define N_HEADS 16
#define N_KV    4
#define DH      128
#define QKV_DIM 3072   // 2048 + 2*4*128
#define TT      2048   // T
#define BB      2      // B
#define ROWS    (BB*TT)  // 4096

// Packed QKV layout in d_out (u16 offsets). Written by gemm1 epilogue:
//   Qp[b][h][t][d]   : ((b*16+h)*2048 + t)*128 + d          @ 0
//   Kp[g][t][d]      : (g*2048 + t)*128 + d                 @ 8,388,608   (g=b*4+hk)
//   Vt[g][d][t]      : (g*128 + d)*2048 + t                 @ 10,485,760  (V pre-transposed)
// Total 12,582,912 u16 = 25,165,824 B (same region/lifetime as old QKV).
#define QP_OFF 0u
#define KP_OFF 8388608u
#define VT_OFF 10485760u

typedef unsigned short u16;
typedef short short8 __attribute__((ext_vector_type(8)));
typedef short short4v __attribute__((ext_vector_type(4)));
typedef float float4v __attribute__((ext_vector_type(4)));

__device__ inline u16 f2b(float f) {
    union { float f; unsigned u; } v; v.f = f;
    unsigned r = v.u + 0x7FFF + ((v.u >> 16) & 1);
    return (u16)(r >> 16);
}

// async global->LDS DMA, 16 bytes/lane. LDS dest = wave-uniform base + lane*16.
__device__ inline void async16(const void* g, void* l) {
    __builtin_amdgcn_global_load_lds(
        (const __attribute__((address_space(1))) void*)g,
        (__attribute__((address_space(3))) void*)l, 16, 0, 0);
}

// ---------------------------------------------------------------------------
// 32x32 transpose tile body (shared by prep/attn_wo fused kernels).
// dst[c][r] = bf16(src[r][c + col0]). 256 threads. tile = u16[32][33].
__device__ inline void transpose_tile(const float* __restrict__ src,
                                      u16* __restrict__ dst,
                                      int R, int C, int col0,
                                      int bx, int by, u16* tile) {
    int bc = bx * 32, br = by * 32;
    int tx = threadIdx.x & 31, ty = threadIdx.x >> 5;   // ty 0..7
    for (int i = ty; i < 32; i += 8)
        tile[i * 33 + tx] = f2b(src[(size_t)(br + i) * C + col0 + bc + tx]);
    __syncthreads();
    for (int i = ty; i < 32; i += 8)
        dst[(size_t)(bc + i) * R + br + tx] = tile[tx * 33 + i];
}

// ---------------------------------------------------------------------------
// Fused preprocessing (saves 2 launch gaps):
//   blocks [0, 8192)        : x fp32 -> xb bf16 (vectorized convert)
//   blocks [8192, 12288)    : Wqkv^T cols 0..2047  -> WqkvTA
//   blocks [12288, 14336)   : Wqkv^T cols 2048..3071 -> WqkvTB
__global__ __launch_bounds__(256) void prep_kernel(
    const float* __restrict__ x, u16* __restrict__ xb,
    const float* __restrict__ Wqkv, u16* __restrict__ WA, u16* __restrict__ WB) {
    __shared__ __align__(16) u16 tile[32 * 33];
    int bid = blockIdx.x;
    if (bid < 8192) {
        size_t i = (size_t)bid * 256 + threadIdx.x;
        float4v a = *(const float4v*)(x + i * 4);
        short4v p;
        p[0] = (short)f2b(a[0]); p[1] = (short)f2b(a[1]);
        p[2] = (short)f2b(a[2]); p[3] = (short)f2b(a[3]);
        *(short4v*)(xb + i * 4) = p;
    } else if (bid < 12288) {
        int t = bid - 8192;                     // dim3(64,64)
        transpose_tile(Wqkv, WA, D_MODEL, QKV_DIM, 0, t & 63, t >> 6, tile);
    } else {
        int t = bid - 12288;                    // dim3(32,64)
        transpose_tile(Wqkv, WB, D_MODEL, QKV_DIM, 2048, t & 31, t >> 5, tile);
    }
}

// ---------------------------------------------------------------------------
// m97-style async GEMM v3: C[M,N] = A[M,K] @ Bt[N,K]^T, bf16 in, fp32 accum.
// = round-6 BK=32 structure EXACTLY (16 KB LDS, 2-3 blocks/CU TLP — round 8/9
// proved that residency is the binding constraint: 8-phase @128KB = 3x slow,
// BK=64 @32KB = occupancy 26->15% and 94->105us despite 0 conflicts),
// plus the ONE occupancy-neutral change: chunk-XOR swizzle.
//   LDS[row][c16] = G[row][c16 ^ ((row>>1)&3)]   (4 chunks of 16B per row)
// via pre-swizzled DMA source chunk (linear LDS dest, rule #21); fragment
// reads XOR the same key -> 16 lanes spread 8 banks x 2 = free 2-way
// (was 8-way, 6.29M conflict-cycles/dispatch in rounds 5/6).
// B^T split across two buffers at N-row `nsplit` (workspace tetris).
// ROPE: fused rotary on cols < 2560 (fast hw trig).
// !F32OUT (gemm1): writes the PACKED QKV layout (Qp/Kp/Vt).
template<bool F32OUT, bool ROPE>
__global__ __launch_bounds__(256) void gemm_bt_async(
    const u16* __restrict__ A, const u16* __restrict__ Bt1, const u16* __restrict__ Bt2,
    int nsplit, void* __restrict__ Cv, int M, int N, int K, const int* __restrict__ sp) {
    __shared__ __align__(16) u16 As[128 * 32];   // 8 KB
    __shared__ __align__(16) u16 Bs[128 * 32];   // 8 KB
    const int tid = threadIdx.x;
    const int wave = tid >> 6, lane = tid & 63;
    const int quad = lane >> 4, l16 = lane & 15;
    const int bm = blockIdx.y * 128, bn = blockIdx.x * 128;
    const int wm = (wave >> 1) * 64, wn = (wave & 1) * 64;
    const int srow = wave * 32 + (lane >> 2);
    // source chunk pre-swizzle: row-in-slab = lane>>2, key = (row>>1)&3
    // = (lane>>3)&3 (slab bases are multiples of 16 -> key wave-uniform).
    const int scol = ((lane & 3) ^ ((lane >> 3) & 3)) * 8;
    const int rsw = (l16 >> 1) & 3;             // read-side XOR key
    const u16* Bt = (bn < nsplit) ? (Bt1 + (size_t)bn * K)
                                  : (Bt2 + (size_t)(bn - nsplit) * K);

    float4v acc[4][4] = {};

    for (int k0 = 0; k0 < K; k0 += 32) {
        async16(A + (size_t)(bm + srow) * K + k0 + scol, (char*)As + wave * 2048);
        async16(A + (size_t)(bm + srow + 16) * K + k0 + scol, (char*)As + wave * 2048 + 1024);
        async16(Bt + (size_t)srow * K + k0 + scol, (char*)Bs + wave * 2048);
        async16(Bt + (size_t)(srow + 16) * K + k0 + scol, (char*)Bs + wave * 2048 + 1024);
        __syncthreads();
        short8 af[4], bf[4];
#pragma unroll
        for (int i = 0; i < 4; i++)
            af[i] = *(const short8*)(As + (wm + i * 16 + l16) * 32
                                     + ((quad ^ rsw) * 8));
#pragma unroll
        for (int j = 0; j < 4; j++)
            bf[j] = *(const short8*)(Bs + (wn + j * 16 + l16) * 32
                                     + ((quad ^ rsw) * 8));
#pragma unroll
        for (int i = 0; i < 4; i++)
#pragma unroll
            for (int j = 0; j < 4; j++)
                acc[i][j] = __builtin_amdgcn_mfma_f32_16x16x32_bf16(af[i], bf[j], acc[i][j], 0, 0, 0);
        __syncthreads();
    }
    const int sp0 = ROPE ? *sp : 0;
    // epilogue: C/D layout col=lane&15, row=quad*4+reg (m89/m91-verified).
#pragma unroll
    for (int j = 0; j < 4; j++) {
        int col = bn + wn + j * 16 + l16;
        bool do_rope = ROPE && (col < 2560);
        float inv = 0.f;
        if (do_rope) inv = __expf(-0.14391156816f * (float)((col & 127) >> 1));
#pragma unroll
        for (int i = 0; i < 4; i++) {
            int row0 = bm + wm + i * 16 + quad * 4;
#pragma unroll
            for (int r = 0; r < 4; r++) {
                float v = acc[i][j][r];
                if (do_rope) {
                    float partner = __shfl_xor(v, 1, 64);
                    float ang = (float)(sp0 + ((row0 + r) & (TT - 1))) * inv;
                    float c = __cosf(ang), s = __sinf(ang);
                    v = (col & 1) ? (partner * s + v * c)
                                  : (v * c - partner * s);
                }
                if (F32OUT) {
                    ((float*)Cv)[(size_t)(row0 + r) * N + col] = v;
                } else {
                    // packed QKV store (region is wave-uniform per j-block)
                    int rw = row0 + r;
                    int bb = rw >> 11, t = rw & 2047;
                    size_t addr;
                    if (col < 2048)
                        addr = QP_OFF + (size_t)(bb * 16 + (col >> 7)) * 262144
                             + (size_t)t * 128 + (col & 127);
                    else if (col < 2560)
                        addr = KP_OFF + (size_t)(bb * 4 + ((col - 2048) >> 7)) * 262144
                             + (size_t)t * 128 + (col & 127);
                    else
                        addr = VT_OFF + (size_t)(bb * 4 + ((col - 2560) >> 7)) * 262144
                             + (size_t)(col & 127) * 2048 + t;
                    ((u16*)Cv)[addr] = f2b(v);
                }
            }
        }
    }
}

// ---------------------------------------------------------------------------
// Fused flash-attention + Wo^T transpose.
//   blocks [0, 512)     : flash attention v10 (unchanged)
//   blocks [512, 4608)  : Wo^T transpose -> WoT
__global__ __launch_bounds__(256, 2) void attn_wo_kernel(
    const u16* __restrict__ qkv, u16* __restrict__ y,
    const float* __restrict__ Wo, u16* __restrict__ WoT) {
    __shared__ __align__(16) u16 Ks[2][32 * 128];   // 2 x 8192 B
    __shared__ __align__(16) u16 Vs[2][128 * 32];   // 2 x 8192 B (V^T: d rows)
    __shared__ __align__(16) u16 Ps[4][32 * 32];    // 8192 B   (total 40960)

    if (blockIdx.x >= 512) {                        // Wo^T transpose blocks
        int t = blockIdx.x - 512;                   // dim3(64,64)
        transpose_tile(Wo, WoT, D_MODEL, D_MODEL, 0, t & 63, t >> 6, (u16*)Ks[0]);
        return;
    }

    const int tid = threadIdx.x;
    const int wave = tid >> 6, lane = tid & 63;
    const int quad = lane >> 4, l16 = lane & 15;
    const int bx = blockIdx.x;
    const int xg = bx & 7;             // XCD group = (b, hk)
    const int b = xg >> 2, hk = xg & 3;
    const int jj = bx >> 3;            // 0..63 within group = XCD stream pos
    // dual-pairing-robust balance map (jj^1 and jj^32 both flip parity only)
    const int h = hk * 4 + 2 * ((jj >> 2) & 1) + (jj & 1);
    const int u = ((jj >> 1) & 1) | (((jj >> 3) & 1) << 1) | (((jj >> 4) & 1) << 2);
    const int p = ((jj >> 5) ^ jj) & 1;
    const int qt = p ? (15 - u) : u;
    const int g = b * 4 + hk;
    const float scale = 0.08838834764831845f;  // 1/sqrt(128)

    // Q fragments in registers (reused every kv-tile): 2 row-groups of 16
    const int wq0 = qt * 128 + wave * 32;
    const u16* qbase = qkv + QP_OFF + (size_t)(b * 16 + h) * 262144;
    short8 qf[2][4];
#pragma unroll
    for (int gi = 0; gi < 2; gi++) {
        const u16* qrow = qbase + (size_t)(wq0 + gi * 16 + l16) * 128;
#pragma unroll
        for (int d = 0; d < 4; d++)
            qf[gi][d] = *(const short8*)(qrow + d * 32 + quad * 8);
    }

    // Oacc[gi][0..7]: O tiles (2 x 16 x 128). Ol[gi]: row-sum l via ones MFMA.
    float4v Oacc[2][8] = {};
    float4v Ol[2] = {};
    const short8 ONES = {(short)0x3F80, (short)0x3F80, (short)0x3F80, (short)0x3F80,
                         (short)0x3F80, (short)0x3F80, (short)0x3F80, (short)0x3F80};

    const int ktmax = 4 * qt + 3;      // kv tiles - 1 (32 kv rows per tile)

    size_t kg[2];
#pragma unroll
    for (int si = 0; si < 2; si++) {
        int kr = wave * 8 + si * 4 + quad;
        kg[si] = (size_t)kr * 128 + (size_t)((l16 ^ (kr & 7)) * 8);
    }
    size_t vg[2];
#pragma unroll
    for (int si = 0; si < 2; si++) {
        int vr = wave * 32 + si * 16 + (lane >> 2);
        vg[si] = (size_t)vr * 2048 + (size_t)((((lane & 3) ^ ((lane >> 3) & 3)) * 8));
    }
    const u16* Kb = qkv + KP_OFF + (size_t)g * 262144;
    const u16* Vb = qkv + VT_OFF + (size_t)g * 262144;

    // kt=0 prefetch (both K and V^T via DMA)
#pragma unroll
    for (int si = 0; si < 2; si++)
        async16(Kb + kg[si], (char*)Ks[0] + wave * 2048 + si * 1024);
#pragma unroll
    for (int si = 0; si < 2; si++)
        async16(Vb + vg[si], (char*)Vs[0] + wave * 2048 + si * 1024);

    for (int kt = 0; kt <= ktmax; kt++) {
        const int cur = kt & 1;
        __syncthreads();   // vmcnt(0)+barrier: DMA for buf[cur] complete
        if (kt < ktmax) {  // prefetch next tile into buf[cur^1]
#pragma unroll
            for (int si = 0; si < 2; si++)
                async16(Kb + (size_t)(kt + 1) * 4096 + kg[si],
                        (char*)Ks[cur ^ 1] + wave * 2048 + si * 1024);
#pragma unroll
            for (int si = 0; si < 2; si++)
                async16(Vb + (size_t)(kt + 1) * 32 + vg[si],
                        (char*)Vs[cur ^ 1] + wave * 2048 + si * 1024);
        }
        const u16* Kcur = Ks[cur];
        const u16* Vcur = Vs[cur];

        float4v S[2][2] = {};
#pragma unroll
        for (int d = 0; d < 4; d++) {
#pragma unroll
            for (int j = 0; j < 2; j++) {
                short8 bk = *(const short8*)(Kcur + (j * 16 + l16) * 128
                                             + (((d * 4 + quad) ^ (l16 & 7)) * 8));
#pragma unroll
                for (int gi = 0; gi < 2; gi++)
                    S[gi][j] = __builtin_amdgcn_mfma_f32_16x16x32_bf16(qf[gi][d], bk, S[gi][j], 0, 0, 0);
            }
        }
        const int kvb = kt * 32 + l16;
        const bool diag = (kt * 32 + 31 > wq0);
#pragma unroll
        for (int gi = 0; gi < 2; gi++) {
            const int qbq = wq0 + gi * 16 + quad * 4;
#pragma unroll
            for (int j = 0; j < 2; j++)
#pragma unroll
                for (int r = 0; r < 4; r++) {
                    bool masked = diag && (kvb + j * 16 > qbq + r);
                    float pv = masked ? 0.f : __expf(S[gi][j][r] * scale);
                    int rq = gi * 16 + quad * 4 + r;
                    int ch = (j * 2 + (l16 >> 3)) ^ ((rq >> 1) & 3);
                    Ps[wave][rq * 32 + ch * 8 + (l16 & 7)] = f2b(pv);
                }
        }
        __asm__ volatile("s_waitcnt lgkmcnt(0)" ::: "memory");
        short8 ap[2];
#pragma unroll
        for (int gi = 0; gi < 2; gi++) {
            int rq = gi * 16 + l16;
            ap[gi] = *(const short8*)(Ps[wave] + rq * 32
                                      + ((quad ^ ((l16 >> 1) & 3)) * 8));
        }
#pragma unroll
        for (int dt = 0; dt < 8; dt++) {
            short8 bv = *(const short8*)(Vcur + (dt * 16 + l16) * 32
                                         + ((quad ^ ((l16 >> 1) & 3)) * 8));
#pragma unroll
            for (int gi = 0; gi < 2; gi++)
                Oacc[gi][dt] = __builtin_amdgcn_mfma_f32_16x16x32_bf16(ap[gi], bv, Oacc[gi][dt], 0, 0, 0);
        }
#pragma unroll
        for (int gi = 0; gi < 2; gi++)
            Ol[gi] = __builtin_amdgcn_mfma_f32_16x16x32_bf16(ap[gi], ONES, Ol[gi], 0, 0, 0);
    }
#pragma unroll
    for (int gi = 0; gi < 2; gi++)
#pragma unroll
        for (int dt = 0; dt < 8; dt++)
#pragma unroll
            for (int r = 0; r < 4; r++) {
                float v = Oacc[gi][dt][r] / Ol[gi][r];
                y[(size_t)(b * TT + wq0 + gi * 16 + quad * 4 + r) * D_MODEL
                  + h * 128 + dt * 16 + l16] = f2b(v);
            }
}

// ---------------------------------------------------------------------------
// Memory plan (ws use = 25,165,824 B, proven available; inputs/out fp32):
//   ws[0, 16.78M):      xb (phases 1-2) -> Y (attn -> gemm2)
//   ws[16.78M, 25.17M): WqkvT rows 0..2047 (gemm1) -> WoT (gemm2)
//   d_out[0, 25.17M):   packed Qp/Kp/Vt bf16 (gemm1 -> attn) -> final fp32 out
//   d_out[25.17M, 33.55M): WqkvT rows 2048..3071 (gemm1 only; dead after)
// Launches: 4 — prep, gemm1 (BK=32 swizzled m97), attn+WoT, gemm2 (same).
extern "C" void kernel_launch(void* const* d_in, const int* in_sizes, int n_in,
                              void* d_out, int out_size, void* d_ws, size_t ws_size,
                              hipStream_t stream) {
    const float* x    = (const float*)d_in[0];   // 4096 x 2048 fp32
    const float* Wqkv = (const float*)d_in[1];   // 2048 x 3072 fp32
    const float* Wo   = (const float*)d_in[2];   // 2048 x 2048 fp32
    const int*   sp   = (const int*)d_in[3];

    char* ws = (char*)d_ws;
    char* dob = (char*)d_out;
    u16*   xb     = (u16*)ws;                    // 4096x2048 bf16
    u16*   Y      = (u16*)ws;                    //    (after gemm1: attn output)
    u16*   WqkvTA = (u16*)(ws + 16777216);       // N-rows 0..2047 of Wqkv^T
    u16*   WoT    = (u16*)(ws + 16777216);       //    (after gemm1)
    u16*   QKVp   = (u16*)d_out;                 // packed Qp/Kp/Vt bf16
    u16*   WqkvTB = (u16*)(dob + 25165824);      // N-rows 2048..3071 of Wqkv^T
    float* out    = (float*)d_out;

    // 1. fused prep: x->bf16 + Wqkv^T (both halves)
    prep_kernel<<<14336, 256, 0, stream>>>(x, xb, Wqkv, WqkvTA, WqkvTB);
    // 2. packed QKV = x @ Wqkv with fused RoPE (BK=32 swizzled m97 structure)
    gemm_bt_async<false, true><<<dim3(QKV_DIM / 128, ROWS / 128), 256, 0, stream>>>(
        xb, WqkvTA, WqkvTB, 2048, QKVp, ROWS, QKV_DIM, D_MODEL, sp);
    // 3. fused flash attention (-> Y, overwrites xb) + Wo^T (-> dead WqkvTA)
    attn_wo_kernel<<<4608, 256, 0, stream>>>(QKVp, Y, Wo, WoT);
    // 4. out = Y @ Wo -> fp32 (overwrites packed QKV + WqkvTB, dead)
    gemm_bt_async<true, false><<<dim3(D_MODEL / 128, ROWS / 128), 256, 0, stream>>>(
        Y, WoT, WoT, D_MODEL, out, ROWS, D_MODEL, D_MODEL, sp);
}